// Round 1
// baseline (45925.616 us; speedup 1.0000x reference)
//
#include <hip/hip_runtime.h>

// 2-layer GRU decoder, persistent kernel.
// B=128, T=1024, H=200, IN0=8, OUT=4.
// Decomposition: 16 batch-groups (8 batch each) x 16 hidden-slice blocks (13 dims,
// last block 5). Weights for each block's slice live in LDS for all 1024 steps.
// Layer-pipelined: phase t computes h0(t), h1(t-1), out(t-2) -> 1 barrier/step.
// h state double-buffered in d_ws; per-group device-scope atomic barrier.

#define TT   1024
#define HH   200
#define NB   8
#define HS   13
#define WPAD 204   // padded LDS row stride (dwords); 204 % 32 = 12 -> conflict-free

__device__ __forceinline__ float sigm(float v) { return 1.0f / (1.0f + __expf(-v)); }
__device__ __forceinline__ float tanh_fast(float v) {
  // |v| <= ~20 in this model (see bounds in notes): exp stays finite.
  float e = __expf(-2.0f * v);
  return (1.0f - e) / (1.0f + e);
}

__global__ __launch_bounds__(256, 1) void gru2_persistent(
    const float* __restrict__ x,
    const float* __restrict__ Wih0, const float* __restrict__ Whh0,
    const float* __restrict__ bih0, const float* __restrict__ bhh0,
    const float* __restrict__ Wih1, const float* __restrict__ Whh1,
    const float* __restrict__ bih1, const float* __restrict__ bhh1,
    const float* __restrict__ Wfc,  const float* __restrict__ bfc,
    float* __restrict__ out,
    float* __restrict__ h0g, float* __restrict__ h1g, int* __restrict__ bars)
{
  // Weight rows: [0,3hs) = W_hh0 (dot h0), [3hs,6hs) = W_ih1 (dot h0),
  //              [6hs,9hs) = W_hh1 (dot h1). Gate order within each: r, z, n.
  __shared__ float Wl[117][WPAD];
  __shared__ float Wi0[39][8];
  __shared__ float Wf[4][WPAD];
  __shared__ float bi0[39], bh0[39], bi1[39], bh1[39], bf[4];
  __shared__ float h0l[NB][WPAD], h1l[NB][WPAD];
  __shared__ float D[117][NB];
  __shared__ float xc[NB][8];

  const int tid = threadIdx.x;
  const int g   = blockIdx.x & 15;   // group = bid&15 -> group's 16 blocks land on one XCD
  const int s   = blockIdx.x >> 4;   // hidden-slice index
  const int b0  = g * NB;
  const int j0  = s * HS;
  const int hs  = (HH - j0 < HS) ? (HH - j0) : HS;   // 13 (s<15) or 5 (s==15)
  const int R      = 9 * hs;                         // 117 or 45
  const int h0rows = 6 * hs;                         // rows dotted with h0

  // ---- one-time weight preload into LDS ----
  const int th = 3 * hs;
  for (int u = tid; u < R * 50; u += 256) {
    int r = u / 50, kc = (u - r * 50) * 4;
    int m = r / th;
    int rr = r - m * th;
    int q = rr / hs, jj = rr - q * hs;
    const float* src = (m == 0) ? Whh0 : ((m == 1) ? Wih1 : Whh1);
    *(float4*)&Wl[r][kc] = *(const float4*)&src[(q * HH + j0 + jj) * HH + kc];
  }
  for (int u = tid; u < th * 8; u += 256) {
    int rr = u >> 3, c = u & 7;
    int q = rr / hs, jj = rr - q * hs;
    Wi0[rr][c] = Wih0[(q * HH + j0 + jj) * 8 + c];
  }
  for (int u = tid; u < th; u += 256) {
    int q = u / hs, jj = u - q * hs;
    int grow = q * HH + j0 + jj;
    bi0[u] = bih0[grow]; bh0[u] = bhh0[grow];
    bi1[u] = bih1[grow]; bh1[u] = bhh1[grow];
  }
  for (int u = tid; u < 4 * HH; u += 256) { int o = u / HH; Wf[o][u - o * HH] = Wfc[u]; }
  if (tid < 4) bf[tid] = bfc[tid];

  // ---- per-lane dot-pass setup ----
  const int rt = tid >> 3, bb = tid & 7;
  const float* hp0 = h0l[bb];
  const float* hp1 = h1l[bb];
  int u0 = rt, u1 = rt + 32, u2 = rt + 64, u3 = rt + 96;
  if (u1 > R - 1) u1 = R - 1;       // clamps only when hs==5
  if (u3 > R - 1) u3 = R - 1;       // clamps when hs==13, rt>=21
  const float* p2  = (u2 < h0rows) ? hp0 : hp1;  // hs==13: only pass 2 is mixed
  const float* p0m = (u0 < h0rows) ? hp0 : hp1;  // hs==5:  only pass 0 is mixed

  int* bar = &bars[g * 16];  // 64B stride between group counters

  const int cj = tid >> 3, cb = tid & 7;

  for (int t = 0; t <= TT + 1; ++t) {
    // ---- stage h0(t-1), h1(t-2) from global double-buffers ----
    const float* h0src = h0g + ((t + 1) & 1) * (128 * HH);
    const float* h1src = h1g + (t & 1) * (128 * HH);
    for (int u = tid; u < NB * 50; u += 256) {
      int b = u / 50, kc = (u - b * 50) * 4;
      *(float4*)&h0l[b][kc] = *(const float4*)&h0src[(b0 + b) * HH + kc];
      *(float4*)&h1l[b][kc] = *(const float4*)&h1src[(b0 + b) * HH + kc];
    }
    if (tid < 64 && t < TT) {   // inputs for h0(t): tf + emotion
      int b = tid >> 3, c = tid & 7;
      float v;
      if (c < 4) v = (t == 0) ? 1.0f : x[((b0 + b) * TT + (t - 1)) * 8 + c];
      else       v = x[(b0 + b) * TT * 8 + c];     // x[b][0][4..7] = emotion
      xc[b][c] = v;
    }
    __syncthreads();

    // ---- dot products (117 rows x 8 batch, K=200) ----
    if (t <= TT) {
      if (hs == HS) {
        float a0 = 0.f, a1 = 0.f, a2 = 0.f, a3 = 0.f;
        for (int k = 0; k < HH; k += 4) {
          float4 xa = *(const float4*)(hp0 + k);   // passes 0,1 (rows < 64 < 78)
          float4 xb = *(const float4*)(p2 + k);    // pass 2 (mixed at 78)
          float4 xd = *(const float4*)(hp1 + k);   // pass 3 (rows >= 96 > 78)
          float4 w0 = *(const float4*)&Wl[u0][k];
          float4 w1 = *(const float4*)&Wl[u1][k];
          float4 w2 = *(const float4*)&Wl[u2][k];
          float4 w3 = *(const float4*)&Wl[u3][k];
          a0 += w0.x * xa.x + w0.y * xa.y + w0.z * xa.z + w0.w * xa.w;
          a1 += w1.x * xa.x + w1.y * xa.y + w1.z * xa.z + w1.w * xa.w;
          a2 += w2.x * xb.x + w2.y * xb.y + w2.z * xb.z + w2.w * xb.w;
          a3 += w3.x * xd.x + w3.y * xd.y + w3.z * xd.z + w3.w * xd.w;
        }
        D[u0][bb] = a0;
        D[u1][bb] = a1;
        D[u2][bb] = a2;
        if (rt + 96 < R) D[u3][bb] = a3;
      } else {
        float a0 = 0.f, a1 = 0.f;
        for (int k = 0; k < HH; k += 4) {
          float4 xa = *(const float4*)(p0m + k);   // pass 0 (mixed at 30)
          float4 xb = *(const float4*)(hp1 + k);   // pass 1 (rows >= 32 > 30)
          float4 w0 = *(const float4*)&Wl[u0][k];
          float4 w1 = *(const float4*)&Wl[u1][k];
          a0 += w0.x * xa.x + w0.y * xa.y + w0.z * xa.z + w0.w * xa.w;
          a1 += w1.x * xb.x + w1.y * xb.y + w1.z * xb.z + w1.w * xb.w;
        }
        D[u0][bb] = a0;
        if (rt + 32 < R) D[rt + 32][bb] = a1;
      }
    }
    __syncthreads();

    // ---- gate combine + state update ----
    if (cj < hs) {
      if (t < TT) {                       // h0(t)
        float ir = bi0[cj], iz = bi0[hs + cj], in_ = bi0[2 * hs + cj];
        #pragma unroll
        for (int c = 0; c < 8; ++c) {
          float xv = xc[cb][c];
          ir  += Wi0[cj][c] * xv;
          iz  += Wi0[hs + cj][c] * xv;
          in_ += Wi0[2 * hs + cj][c] * xv;
        }
        float hr = D[cj][cb] + bh0[cj];
        float hz = D[hs + cj][cb] + bh0[hs + cj];
        float hn = D[2 * hs + cj][cb] + bh0[2 * hs + cj];
        float r = sigm(ir + hr), z = sigm(iz + hz);
        float n = tanh_fast(in_ + r * hn);
        float hv = h0l[cb][j0 + cj];
        h0g[(t & 1) * (128 * HH) + (b0 + cb) * HH + j0 + cj] = (1.0f - z) * n + z * hv;
      }
      if (t >= 1 && t <= TT) {            // h1(t-1)
        float ir  = D[3 * hs + cj][cb] + bi1[cj];
        float iz  = D[4 * hs + cj][cb] + bi1[hs + cj];
        float in_ = D[5 * hs + cj][cb] + bi1[2 * hs + cj];
        float hr  = D[6 * hs + cj][cb] + bh1[cj];
        float hz  = D[7 * hs + cj][cb] + bh1[hs + cj];
        float hn  = D[8 * hs + cj][cb] + bh1[2 * hs + cj];
        float r = sigm(ir + hr), z = sigm(iz + hz);
        float n = tanh_fast(in_ + r * hn);
        float hv = h1l[cb][j0 + cj];
        h1g[((t + 1) & 1) * (128 * HH) + (b0 + cb) * HH + j0 + cj] = (1.0f - z) * n + z * hv;
      }
    }
    if (s == 15 && t >= 2 && tid >= 128 && tid < 160) {   // out(t-2), light block only
      int ob = (tid - 128) >> 2, oo = tid & 3;
      float acc = bf[oo];
      for (int k = 0; k < HH; k += 4) {
        float4 wv = *(const float4*)&Wf[oo][k];
        float4 hv = *(const float4*)&h1l[ob][k];
        acc += wv.x * hv.x + wv.y * hv.y + wv.z * hv.z + wv.w * hv.w;
      }
      out[((b0 + ob) * TT + (t - 2)) * 4 + oo] = tanh_fast(acc);
    }

    // ---- per-group device-scope barrier ----
    __threadfence();       // release own stores device-wide (L2 writeback)
    __syncthreads();
    if (tid == 0) {
      __hip_atomic_fetch_add(bar, 1, __ATOMIC_RELEASE, __HIP_MEMORY_SCOPE_AGENT);
      const int target = 16 * (t + 1);
      while (__hip_atomic_load(bar, __ATOMIC_ACQUIRE, __HIP_MEMORY_SCOPE_AGENT) < target)
        __builtin_amdgcn_s_sleep(1);
    }
    __syncthreads();
    __threadfence();       // acquire: invalidate vL1 before next stage reads
  }
}

extern "C" void kernel_launch(void* const* d_in, const int* in_sizes, int n_in,
                              void* d_out, int out_size, void* d_ws, size_t ws_size,
                              hipStream_t stream) {
  float* ws = (float*)d_ws;
  // ws layout (floats): h0g[2][128][200] @0, h1g[2][128][200] @51200,
  // barrier counters (16 x 64B-strided ints) @102400. Total 410,624 B.
  hipMemsetAsync(d_ws, 0, (size_t)(102400 + 256) * sizeof(float), stream);
  gru2_persistent<<<256, 256, 0, stream>>>(
      (const float*)d_in[0],
      (const float*)d_in[1], (const float*)d_in[2],
      (const float*)d_in[3], (const float*)d_in[4],
      (const float*)d_in[5], (const float*)d_in[6],
      (const float*)d_in[7], (const float*)d_in[8],
      (const float*)d_in[9], (const float*)d_in[10],
      (float*)d_out, ws, ws + 51200, (int*)(ws + 102400));
}

// Round 2
// 10728.099 us; speedup vs baseline: 4.2809x; 4.2809x over previous
//
#include <hip/hip_runtime.h>

// 2-layer GRU decoder, persistent kernel. B=128, T=1024, H=200, IN0=8, OUT=4.
// 16 batch-groups (8 batch each) x 16 hidden-slice blocks (13 dims, last 5).
// Weights in LDS for all steps. Layer-pipelined: phase t computes h0(t),
// h1(t-1), out(t-2) -> 1 barrier/step.
//
// R1 change: ALL cross-block communication (h state, barrier counter) uses
// relaxed SYSTEM-scope atomics -> global ops with sc0 sc1 (operate at the
// Infinity Cache coherence point, bypass L1/L2). NO acquire/release fences:
// agent/system ACQ/REL lower to buffer_inv / buffer_wbl2 (whole-L2
// invalidate/writeback) which was ~44 us/step in R0. Ordering guarantees:
// __syncthreads() drains vmcnt(0) (stores committed at LLC) before the
// counter increment; post-poll loads are control-dependent + in-order issue.

#define TT   1024
#define HH   200
#define NB   8
#define HS   13
#define WPAD 204   // padded LDS row stride (dwords); 204 % 32 = 12 -> conflict-free

__device__ __forceinline__ float sigm(float v) { return 1.0f / (1.0f + __expf(-v)); }
__device__ __forceinline__ float tanh_fast(float v) {
  float e = __expf(-2.0f * v);
  return (1.0f - e) / (1.0f + e);
}

__device__ __forceinline__ float llc_load(const float* p) {
  return __hip_atomic_load((const float*)p, __ATOMIC_RELAXED, __HIP_MEMORY_SCOPE_SYSTEM);
}
__device__ __forceinline__ void llc_store(float* p, float v) {
  __hip_atomic_store(p, v, __ATOMIC_RELAXED, __HIP_MEMORY_SCOPE_SYSTEM);
}

__global__ __launch_bounds__(256, 1) void gru2_persistent(
    const float* __restrict__ x,
    const float* __restrict__ Wih0, const float* __restrict__ Whh0,
    const float* __restrict__ bih0, const float* __restrict__ bhh0,
    const float* __restrict__ Wih1, const float* __restrict__ Whh1,
    const float* __restrict__ bih1, const float* __restrict__ bhh1,
    const float* __restrict__ Wfc,  const float* __restrict__ bfc,
    float* __restrict__ out,
    float* __restrict__ h0g, float* __restrict__ h1g, int* __restrict__ bars)
{
  // Weight rows: [0,3hs) = W_hh0 (dot h0), [3hs,6hs) = W_ih1 (dot h0),
  //              [6hs,9hs) = W_hh1 (dot h1). Gate order within each: r, z, n.
  __shared__ float Wl[117][WPAD];
  __shared__ float Wi0[39][8];
  __shared__ float Wf[4][WPAD];
  __shared__ float bi0[39], bh0[39], bi1[39], bh1[39], bf[4];
  __shared__ float h0l[NB][WPAD], h1l[NB][WPAD];
  __shared__ float D[117][NB];
  __shared__ float xc[NB][8];

  const int tid = threadIdx.x;
  const int g   = blockIdx.x & 15;   // batch-group
  const int s   = blockIdx.x >> 4;   // hidden-slice index
  const int b0  = g * NB;
  const int j0  = s * HS;
  const int hs  = (HH - j0 < HS) ? (HH - j0) : HS;   // 13 (s<15) or 5 (s==15)
  const int R      = 9 * hs;                         // 117 or 45
  const int h0rows = 6 * hs;                         // rows dotted with h0

  // ---- one-time weight preload into LDS ----
  const int th = 3 * hs;
  for (int u = tid; u < R * 50; u += 256) {
    int r = u / 50, kc = (u - r * 50) * 4;
    int m = r / th;
    int rr = r - m * th;
    int q = rr / hs, jj = rr - q * hs;
    const float* src = (m == 0) ? Whh0 : ((m == 1) ? Wih1 : Whh1);
    *(float4*)&Wl[r][kc] = *(const float4*)&src[(q * HH + j0 + jj) * HH + kc];
  }
  for (int u = tid; u < th * 8; u += 256) {
    int rr = u >> 3, c = u & 7;
    int q = rr / hs, jj = rr - q * hs;
    Wi0[rr][c] = Wih0[(q * HH + j0 + jj) * 8 + c];
  }
  for (int u = tid; u < th; u += 256) {
    int q = u / hs, jj = u - q * hs;
    int grow = q * HH + j0 + jj;
    bi0[u] = bih0[grow]; bh0[u] = bhh0[grow];
    bi1[u] = bih1[grow]; bh1[u] = bhh1[grow];
  }
  for (int u = tid; u < 4 * HH; u += 256) { int o = u / HH; Wf[o][u - o * HH] = Wfc[u]; }
  if (tid < 4) bf[tid] = bfc[tid];

  // ---- per-lane dot-pass setup ----
  const int rt = tid >> 3, bb = tid & 7;
  const float* hp0 = h0l[bb];
  const float* hp1 = h1l[bb];
  int u0 = rt, u1 = rt + 32, u2 = rt + 64, u3 = rt + 96;
  if (u1 > R - 1) u1 = R - 1;       // clamps only when hs==5
  if (u3 > R - 1) u3 = R - 1;       // clamps when hs==13, rt>=21
  const float* p2  = (u2 < h0rows) ? hp0 : hp1;  // hs==13: only pass 2 is mixed
  const float* p0m = (u0 < h0rows) ? hp0 : hp1;  // hs==5:  only pass 0 is mixed

  int* bar = &bars[g * 64];  // 256B stride between group counters

  const int cj = tid >> 3, cb = tid & 7;

  for (int t = 0; t <= TT + 1; ++t) {
    // ---- stage h0(t-1), h1(t-2) from LLC double-buffers ----
    const float* h0src = h0g + ((t + 1) & 1) * (128 * HH);
    const float* h1src = h1g + (t & 1) * (128 * HH);
    if (tid < HH) {
      #pragma unroll
      for (int b = 0; b < NB; ++b) {
        h0l[b][tid] = llc_load(&h0src[(b0 + b) * HH + tid]);
        h1l[b][tid] = llc_load(&h1src[(b0 + b) * HH + tid]);
      }
    }
    if (tid < 64 && t < TT) {   // inputs for h0(t): tf + emotion (plain cached loads)
      int b = tid >> 3, c = tid & 7;
      float v;
      if (c < 4) v = (t == 0) ? 1.0f : x[((b0 + b) * TT + (t - 1)) * 8 + c];
      else       v = x[(b0 + b) * TT * 8 + c];     // x[b][0][4..7] = emotion
      xc[b][c] = v;
    }
    __syncthreads();

    // ---- dot products (R rows x 8 batch, K=200) ----
    if (t <= TT) {
      if (hs == HS) {
        float a0 = 0.f, a1 = 0.f, a2 = 0.f, a3 = 0.f;
        for (int k = 0; k < HH; k += 4) {
          float4 xa = *(const float4*)(hp0 + k);   // passes 0,1 (rows < 64 < 78)
          float4 xb = *(const float4*)(p2 + k);    // pass 2 (mixed at 78)
          float4 xd = *(const float4*)(hp1 + k);   // pass 3 (rows >= 96 > 78)
          float4 w0 = *(const float4*)&Wl[u0][k];
          float4 w1 = *(const float4*)&Wl[u1][k];
          float4 w2 = *(const float4*)&Wl[u2][k];
          float4 w3 = *(const float4*)&Wl[u3][k];
          a0 += w0.x * xa.x + w0.y * xa.y + w0.z * xa.z + w0.w * xa.w;
          a1 += w1.x * xa.x + w1.y * xa.y + w1.z * xa.z + w1.w * xa.w;
          a2 += w2.x * xb.x + w2.y * xb.y + w2.z * xb.z + w2.w * xb.w;
          a3 += w3.x * xd.x + w3.y * xd.y + w3.z * xd.z + w3.w * xd.w;
        }
        D[u0][bb] = a0;
        D[u1][bb] = a1;
        D[u2][bb] = a2;
        if (rt + 96 < R) D[u3][bb] = a3;
      } else {
        float a0 = 0.f, a1 = 0.f;
        for (int k = 0; k < HH; k += 4) {
          float4 xa = *(const float4*)(p0m + k);   // pass 0 (mixed at 30)
          float4 xb = *(const float4*)(hp1 + k);   // pass 1 (rows >= 32 > 30)
          float4 w0 = *(const float4*)&Wl[u0][k];
          float4 w1 = *(const float4*)&Wl[u1][k];
          a0 += w0.x * xa.x + w0.y * xa.y + w0.z * xa.z + w0.w * xa.w;
          a1 += w1.x * xb.x + w1.y * xb.y + w1.z * xb.z + w1.w * xb.w;
        }
        D[u0][bb] = a0;
        if (rt + 32 < R) D[rt + 32][bb] = a1;
      }
    }
    __syncthreads();

    // ---- gate combine + state update (stores go straight to LLC) ----
    if (cj < hs) {
      if (t < TT) {                       // h0(t)
        float ir = bi0[cj], iz = bi0[hs + cj], in_ = bi0[2 * hs + cj];
        #pragma unroll
        for (int c = 0; c < 8; ++c) {
          float xv = xc[cb][c];
          ir  += Wi0[cj][c] * xv;
          iz  += Wi0[hs + cj][c] * xv;
          in_ += Wi0[2 * hs + cj][c] * xv;
        }
        float hr = D[cj][cb] + bh0[cj];
        float hz = D[hs + cj][cb] + bh0[hs + cj];
        float hn = D[2 * hs + cj][cb] + bh0[2 * hs + cj];
        float r = sigm(ir + hr), z = sigm(iz + hz);
        float n = tanh_fast(in_ + r * hn);
        float hv = h0l[cb][j0 + cj];
        llc_store(&h0g[(t & 1) * (128 * HH) + (b0 + cb) * HH + j0 + cj],
                  (1.0f - z) * n + z * hv);
      }
      if (t >= 1 && t <= TT) {            // h1(t-1)
        float ir  = D[3 * hs + cj][cb] + bi1[cj];
        float iz  = D[4 * hs + cj][cb] + bi1[hs + cj];
        float in_ = D[5 * hs + cj][cb] + bi1[2 * hs + cj];
        float hr  = D[6 * hs + cj][cb] + bh1[cj];
        float hz  = D[7 * hs + cj][cb] + bh1[hs + cj];
        float hn  = D[8 * hs + cj][cb] + bh1[2 * hs + cj];
        float r = sigm(ir + hr), z = sigm(iz + hz);
        float n = tanh_fast(in_ + r * hn);
        float hv = h1l[cb][j0 + cj];
        llc_store(&h1g[((t + 1) & 1) * (128 * HH) + (b0 + cb) * HH + j0 + cj],
                  (1.0f - z) * n + z * hv);
      }
    }
    if (s == 15 && t >= 2 && tid >= 128 && tid < 160) {   // out(t-2), light block only
      int ob = (tid - 128) >> 2, oo = tid & 3;
      float acc = bf[oo];
      for (int k = 0; k < HH; k += 4) {
        float4 wv = *(const float4*)&Wf[oo][k];
        float4 hv = *(const float4*)&h1l[ob][k];
        acc += wv.x * hv.x + wv.y * hv.y + wv.z * hv.z + wv.w * hv.w;
      }
      out[((b0 + ob) * TT + (t - 2)) * 4 + oo] = tanh_fast(acc);
    }

    // ---- per-group barrier at the LLC: no fences, no cache maintenance ----
    __syncthreads();   // compiler emits s_waitcnt vmcnt(0) before s_barrier:
                       // all waves' LLC stores are committed past this point
    if (tid == 0) {
      __hip_atomic_fetch_add(bar, 1, __ATOMIC_RELAXED, __HIP_MEMORY_SCOPE_SYSTEM);
      const int target = 16 * (t + 1);
      while (__hip_atomic_load(bar, __ATOMIC_RELAXED, __HIP_MEMORY_SCOPE_SYSTEM) < target)
        __builtin_amdgcn_s_sleep(1);
    }
    __syncthreads();
  }
}

extern "C" void kernel_launch(void* const* d_in, const int* in_sizes, int n_in,
                              void* d_out, int out_size, void* d_ws, size_t ws_size,
                              hipStream_t stream) {
  float* ws = (float*)d_ws;
  // ws layout (floats): h0g[2][128][200] @0, h1g[2][128][200] @51200,
  // barrier counters (16 x 256B-strided ints) @102400.
  hipMemsetAsync(d_ws, 0, (size_t)(102400 + 1024) * sizeof(float), stream);
  gru2_persistent<<<256, 256, 0, stream>>>(
      (const float*)d_in[0],
      (const float*)d_in[1], (const float*)d_in[2],
      (const float*)d_in[3], (const float*)d_in[4],
      (const float*)d_in[5], (const float*)d_in[6],
      (const float*)d_in[7], (const float*)d_in[8],
      (const float*)d_in[9], (const float*)d_in[10],
      (float*)d_out, ws, ws + 51200, (int*)(ws + 102400));
}

// Round 3
// 3170.145 us; speedup vs baseline: 14.4869x; 3.3841x over previous
//
#include <hip/hip_runtime.h>
#include <hip/hip_bf16.h>

// 2-layer GRU decoder, persistent MFMA kernel. B=128, T=1024, H=200.
// 8 batch-groups (16 batch each) x 16 hidden-slice blocks = 128 blocks.
// R3: weights live in REGISTERS as bf16 hi/lo MFMA A-fragments (112 VGPR/wave);
// per-step GEMM done with mfma_f32_16x16x32_bf16 x3 (hi*hi + hi*lo + lo*hi)
// for fp32-grade precision. h state crosses blocks as packed (hi|lo<<16) uints
// via relaxed system-scope (LLC) atomics; 1 barrier/step as in R2.

#define TT 1024
#define HH 200
#define NB 16
#define HS 13
#define KP 232   // hB row stride in ushorts; 464 B = 29*16 -> b128-aligned

typedef __attribute__((ext_vector_type(8))) short short8;
typedef __attribute__((ext_vector_type(4))) float f32x4;

__device__ __forceinline__ float sigm(float v) { return 1.0f / (1.0f + __expf(-v)); }
__device__ __forceinline__ float tanh_fast(float v) {
  float e = __expf(-2.0f * v);
  return (1.0f - e) / (1.0f + e);
}
__device__ __forceinline__ uint llc_load_u32(const uint* p) {
  return __hip_atomic_load(p, __ATOMIC_RELAXED, __HIP_MEMORY_SCOPE_SYSTEM);
}
__device__ __forceinline__ void llc_store_u32(uint* p, uint v) {
  __hip_atomic_store(p, v, __ATOMIC_RELAXED, __HIP_MEMORY_SCOPE_SYSTEM);
}
__device__ __forceinline__ float bfu2f(ushort u) {
  return __uint_as_float(((uint)u) << 16);
}
__device__ __forceinline__ ushort f2bfu(float f) {
  __hip_bfloat16 b = __float2bfloat16(f);
  return *(ushort*)&b;
}
__device__ __forceinline__ uint packf(float h) {
  ushort hi = f2bfu(h);
  float  fh = bfu2f(hi);
  ushort lo = f2bfu(h - fh);
  return (uint)hi | ((uint)lo << 16);
}

__global__ __launch_bounds__(256, 1) void gru2_mfma(
    const float* __restrict__ x,
    const float* __restrict__ Wih0, const float* __restrict__ Whh0,
    const float* __restrict__ bih0, const float* __restrict__ bhh0,
    const float* __restrict__ Wih1, const float* __restrict__ Whh1,
    const float* __restrict__ bih1, const float* __restrict__ bhh1,
    const float* __restrict__ Wfc,  const float* __restrict__ bfc,
    float* __restrict__ out,
    uint* __restrict__ h0g, uint* __restrict__ h1g, int* __restrict__ bars)
{
  // LDS: bf16 hi/lo planes of h0,h1 (B-operand layout), D results, misc.
  __shared__ __align__(16) ushort hBh[2][NB][KP];
  __shared__ __align__(16) ushort hBl[2][NB][KP];
  __shared__ float D[117][17];
  __shared__ float Wi0[39][8];
  __shared__ float bi0[39], bh0[39], bi1[39], bh1[39], bfs[4];
  __shared__ float xc[NB][8];

  const int tid  = threadIdx.x;
  const int wave = tid >> 6;
  const int lane = tid & 63;
  const int m15  = lane & 15;   // MFMA row (A) / col (B,C)
  const int q    = lane >> 4;   // MFMA quad

  const int g  = blockIdx.x & 7;    // batch-group; bid%8 -> same XCD (perf only)
  const int s  = blockIdx.x >> 3;   // hidden-slice
  const int b0 = g * NB;
  const int j0 = s * HS;
  const int hs = (HH - j0 < HS) ? (HH - j0) : HS;   // 13 (s<15) or 5 (s==15)
  const int th   = 3 * hs;
  const int h0r  = 6 * hs;                          // rows dotted with h0
  const int T0   = (h0r + 15) >> 4;                 // 5 or 2  (h0 tiles)
  const int NT   = T0 + ((th + 15) >> 4);           // 8 or 3  (total tiles)
  const bool isOut = (s == 15);

  // ---- one-time: weight A-fragments into registers (hi/lo bf16) ----
  short8 Ah[2][7], Al[2][7];
  #pragma unroll
  for (int mt = 0; mt < 2; ++mt) {
    const int T = wave * 2 + mt;
    const bool fc  = isOut && (wave == 2) && (mt == 0);
    const bool val = fc || (T < NT);
    #pragma unroll
    for (int kt = 0; kt < 7; ++kt) {
      short8 vh = {0,0,0,0,0,0,0,0}, vl = {0,0,0,0,0,0,0,0};
      #pragma unroll
      for (int j = 0; j < 8; ++j) {
        const int k = kt * 32 + q * 8 + j;
        float w = 0.0f;
        if (val && k < HH) {
          if (fc) {
            if (m15 < 4) w = Wfc[m15 * HH + k];
          } else {
            const int p = T * 16 + m15;
            int r = -1;
            if (p < h0r) r = p;
            else if (p >= T0 * 16 && (p - T0 * 16) < th) r = h0r + (p - T0 * 16);
            if (r >= 0) {
              const int m  = r / th, rr = r - m * th;
              const int qq = rr / hs, jj = rr - qq * hs;
              const float* src = (m == 0) ? Whh0 : ((m == 1) ? Wih1 : Whh1);
              w = src[(qq * HH + j0 + jj) * HH + k];
            }
          }
        }
        const ushort uh = f2bfu(w);
        const ushort ul = f2bfu(w - bfu2f(uh));
        vh[j] = (short)uh; vl[j] = (short)ul;
      }
      Ah[mt][kt] = vh; Al[mt][kt] = vl;
    }
  }

  // ---- one-time: small LDS tables ----
  for (int u = tid; u < th * 8; u += 256) {
    int rr = u >> 3, c = u & 7;
    int qq = rr / hs, jj = rr - qq * hs;
    Wi0[rr][c] = Wih0[(qq * HH + j0 + jj) * 8 + c];
  }
  for (int u = tid; u < th; u += 256) {
    int qq = u / hs, jj = u - qq * hs;
    int grow = qq * HH + j0 + jj;
    bi0[u] = bih0[grow]; bh0[u] = bhh0[grow];
    bi1[u] = bih1[grow]; bh1[u] = bhh1[grow];
  }
  if (tid < 4) bfs[tid] = bfc[tid];
  for (int u = tid; u < 2 * NB * KP / 2; u += 256) ((uint*)hBh)[u] = 0;  // zero pads
  for (int u = tid; u < 2 * NB * KP / 2; u += 256) ((uint*)hBl)[u] = 0;
  __syncthreads();

  int* bar = &bars[g * 64];
  const int cj = tid >> 4, cb = tid & 15;   // gate-combine indices

  for (int t = 0; t <= TT + 1; ++t) {
    // ---- stage h0(t-1), h1(t-2): packed bf16 hi/lo from LLC -> LDS planes ----
    const uint* h0src = h0g + ((t + 1) & 1) * (128 * HH);
    const uint* h1src = h1g + (t & 1) * (128 * HH);
    uint tmp[25];                          // 2 states x 16 b x 200 k = 6400 = 25*256
    #pragma unroll
    for (int i = 0; i < 25; ++i) {
      const int u  = tid + i * 256;
      const int st = u / 3200, rem = u - st * 3200;
      const int b  = rem / 200, k = rem - b * 200;
      tmp[i] = llc_load_u32(&(st ? h1src : h0src)[(b0 + b) * HH + k]);
    }
    #pragma unroll
    for (int i = 0; i < 25; ++i) {
      const int u  = tid + i * 256;
      const int st = u / 3200, rem = u - st * 3200;
      const int b  = rem / 200, k = rem - b * 200;
      hBh[st][b][k] = (ushort)(tmp[i] & 0xffff);
      hBl[st][b][k] = (ushort)(tmp[i] >> 16);
    }
    if (tid < 128 && t < TT) {             // inputs for h0(t): tf + emotion
      int b = tid >> 3, c = tid & 7;
      float v;
      if (c < 4) v = (t == 0) ? 1.0f : x[((b0 + b) * TT + (t - 1)) * 8 + c];
      else       v = x[(b0 + b) * TT * 8 + c];
      xc[b][c] = v;
    }
    __syncthreads();

    // ---- MFMA: D[rows x 16 batch] = W * h  (bf16x3) ----
    #pragma unroll
    for (int mt = 0; mt < 2; ++mt) {
      const int T = wave * 2 + mt;
      const bool fc  = isOut && (wave == 2) && (mt == 0);
      const bool val = fc || (T < NT);
      if (!val) continue;
      const int st = fc ? 1 : ((T < T0) ? 0 : 1);
      const ushort* Bh = &hBh[st][m15][0];
      const ushort* Bl = &hBl[st][m15][0];
      f32x4 acc = {0.f, 0.f, 0.f, 0.f};
      #pragma unroll
      for (int kt = 0; kt < 7; ++kt) {
        const short8 bh = *(const short8*)&Bh[kt * 32 + q * 8];
        const short8 bl = *(const short8*)&Bl[kt * 32 + q * 8];
        acc = __builtin_amdgcn_mfma_f32_16x16x32_bf16(Ah[mt][kt], bh, acc, 0, 0, 0);
        acc = __builtin_amdgcn_mfma_f32_16x16x32_bf16(Ah[mt][kt], bl, acc, 0, 0, 0);
        acc = __builtin_amdgcn_mfma_f32_16x16x32_bf16(Al[mt][kt], bh, acc, 0, 0, 0);
      }
      if (fc) {                              // FC head: out(t-2)
        if (t >= 2) {
          #pragma unroll
          for (int i = 0; i < 4; ++i) {
            const int p = q * 4 + i;
            if (p < 4)
              out[((b0 + m15) * TT + (t - 2)) * 4 + p] = tanh_fast(acc[i] + bfs[p]);
          }
        }
      } else {
        #pragma unroll
        for (int i = 0; i < 4; ++i) {
          const int p = T * 16 + q * 4 + i;
          int r = -1;
          if (p < h0r) r = p;
          else if (p >= T0 * 16 && (p - T0 * 16) < th) r = h0r + (p - T0 * 16);
          if (r >= 0) D[r][m15] = acc[i];
        }
      }
    }
    __syncthreads();

    // ---- gate combine + state update (packed stores to LLC) ----
    if (cj < hs) {
      const float hv0 = bfu2f(hBh[0][cb][j0 + cj]) + bfu2f(hBl[0][cb][j0 + cj]);
      const float hv1 = bfu2f(hBh[1][cb][j0 + cj]) + bfu2f(hBl[1][cb][j0 + cj]);
      if (t < TT) {                       // h0(t)
        float ir = bi0[cj], iz = bi0[hs + cj], in_ = bi0[2 * hs + cj];
        #pragma unroll
        for (int c = 0; c < 8; ++c) {
          const float xv = xc[cb][c];
          ir  += Wi0[cj][c] * xv;
          iz  += Wi0[hs + cj][c] * xv;
          in_ += Wi0[2 * hs + cj][c] * xv;
        }
        const float hr = D[cj][cb] + bh0[cj];
        const float hz = D[hs + cj][cb] + bh0[hs + cj];
        const float hn = D[2 * hs + cj][cb] + bh0[2 * hs + cj];
        const float r = sigm(ir + hr), z = sigm(iz + hz);
        const float n = tanh_fast(in_ + r * hn);
        llc_store_u32(&h0g[(t & 1) * (128 * HH) + (b0 + cb) * HH + j0 + cj],
                      packf((1.0f - z) * n + z * hv0));
      }
      if (t >= 1 && t <= TT) {            // h1(t-1)
        const float ir  = D[3 * hs + cj][cb] + bi1[cj];
        const float iz  = D[4 * hs + cj][cb] + bi1[hs + cj];
        const float in_ = D[5 * hs + cj][cb] + bi1[2 * hs + cj];
        const float hr  = D[6 * hs + cj][cb] + bh1[cj];
        const float hz  = D[7 * hs + cj][cb] + bh1[hs + cj];
        const float hn  = D[8 * hs + cj][cb] + bh1[2 * hs + cj];
        const float r = sigm(ir + hr), z = sigm(iz + hz);
        const float n = tanh_fast(in_ + r * hn);
        llc_store_u32(&h1g[((t + 1) & 1) * (128 * HH) + (b0 + cb) * HH + j0 + cj],
                      packf((1.0f - z) * n + z * hv1));
      }
    }

    // ---- per-group barrier at the LLC ----
    __syncthreads();   // s_waitcnt vmcnt(0) before s_barrier: stores at LLC
    if (tid == 0) {
      __hip_atomic_fetch_add(bar, 1, __ATOMIC_RELAXED, __HIP_MEMORY_SCOPE_SYSTEM);
      const int target = 16 * (t + 1);
      while (__hip_atomic_load(bar, __ATOMIC_RELAXED, __HIP_MEMORY_SCOPE_SYSTEM) < target)
        __builtin_amdgcn_s_sleep(1);
    }
    __syncthreads();
  }
}

extern "C" void kernel_launch(void* const* d_in, const int* in_sizes, int n_in,
                              void* d_out, int out_size, void* d_ws, size_t ws_size,
                              hipStream_t stream) {
  uint* ws = (uint*)d_ws;
  // ws layout (u32): h0g[2][128][200] @0, h1g[2][128][200] @51200,
  // barrier counters (8 x 256B-strided ints) @102400.
  hipMemsetAsync(d_ws, 0, (size_t)(102400 + 512) * sizeof(uint), stream);
  gru2_mfma<<<128, 256, 0, stream>>>(
      (const float*)d_in[0],
      (const float*)d_in[1], (const float*)d_in[2],
      (const float*)d_in[3], (const float*)d_in[4],
      (const float*)d_in[5], (const float*)d_in[6],
      (const float*)d_in[7], (const float*)d_in[8],
      (const float*)d_in[9], (const float*)d_in[10],
      (float*)d_out, ws, ws + 51200, (int*)(ws + 102400));
}